// Round 6
// baseline (1053.887 us; speedup 1.0000x reference)
//
#include <hip/hip_runtime.h>

#define N_USERS 200000
#define N_ITEMS 100000
#define NN      300000        // N_USERS + N_ITEMS
#define DIM     64
#define N_EDGES 9600000
#define BATCH   16384
#define BSH2    10            // 1024 rows per bucket
#define NB2     293           // ceil(NN / 1024)
#define CHUNK2  4096          // edges per bin_sort block

// ---------------- init: E0 = concat(user_emb, item_emb) ----------------
__global__ void copy_init(const float* __restrict__ ue, const float* __restrict__ ie,
                          float* __restrict__ E) {
    const size_t nU = (size_t)N_USERS * DIM / 4;
    const size_t nT = (size_t)NN * DIM / 4;
    const float4* u4 = (const float4*)ue;
    const float4* i4 = (const float4*)ie;
    float4* E4 = (float4*)E;
    size_t stride = (size_t)gridDim.x * blockDim.x;
    for (size_t k = (size_t)blockIdx.x * blockDim.x + threadIdx.x; k < nT; k += stride)
        E4[k] = (k < nU) ? u4[k] : i4[k - nU];
}

// ---------------- bucket-level histogram (LDS-staged, ~300K global adds total) ----------------
__global__ void hist_buckets(const int* __restrict__ rows, int* __restrict__ bcnt) {
    __shared__ int h[NB2];
    for (int i = threadIdx.x; i < NB2; i += blockDim.x) h[i] = 0;
    __syncthreads();
    int stride = gridDim.x * blockDim.x;
    for (int e = blockIdx.x * blockDim.x + threadIdx.x; e < N_EDGES; e += stride)
        atomicAdd(&h[rows[e] >> BSH2], 1);
    __syncthreads();
    for (int i = threadIdx.x; i < NB2; i += blockDim.x)
        if (h[i]) atomicAdd(&bcnt[i], h[i]);
}

// exclusive scan of 293 bucket counts; writes bstart[] and seeds gfill[]
__global__ void scan_buckets(const int* __restrict__ bcnt, int* __restrict__ bstart,
                             int* __restrict__ gfill) {
    __shared__ int s[512];
    int tid = threadIdx.x;
    int x = (tid < NB2) ? bcnt[tid] : 0;
    s[tid] = x;
    __syncthreads();
    for (int off = 1; off < 512; off <<= 1) {
        int t = (tid >= off) ? s[tid - off] : 0;
        __syncthreads();
        s[tid] += t;
        __syncthreads();
    }
    if (tid < NB2) { int v = s[tid] - x; bstart[tid] = v; gfill[tid] = v; }
    if (tid == 0) bstart[NB2] = N_EDGES;
}

// ---------------- pass 1: per-block counting sort by 1024-row bucket ----------------
__global__ __launch_bounds__(256) void bin_sort(const int* __restrict__ rows,
                                                const int* __restrict__ cols,
                                                const float* __restrict__ vals,
                                                int* __restrict__ gfill,
                                                int2* __restrict__ estage) {
    __shared__ int  hist[NB2 + 1];
    __shared__ int  sc[NB2 + 1];
    __shared__ int  gbase[NB2];
    __shared__ int  rankc[NB2];
    __shared__ int2 st[CHUNK2];
    __shared__ int  dstb[CHUNK2];

    int tid = threadIdx.x;
    int e0 = blockIdx.x * CHUNK2;
    int e1 = min(e0 + CHUNK2, N_EDGES);
    int n  = e1 - e0;

    for (int i = tid; i <= NB2; i += 256) { hist[i] = 0; sc[i] = 0; }
    __syncthreads();

    for (int e = e0 + tid; e < e1; e += 256)
        atomicAdd(&hist[rows[e] >> BSH2], 1);
    __syncthreads();

    for (int i = tid; i < NB2; i += 256) sc[i] = hist[i];
    __syncthreads();

    for (int off = 1; off < NB2; off <<= 1) {
        int i0 = tid, i1 = tid + 256;
        int a0 = 0, a1 = 0;
        if (i0 < NB2 && i0 >= off) a0 = sc[i0 - off];
        if (i1 < NB2 && i1 >= off) a1 = sc[i1 - off];
        __syncthreads();
        if (i0 < NB2 && i0 >= off) sc[i0] += a0;
        if (i1 < NB2 && i1 >= off) sc[i1] += a1;
        __syncthreads();
    }

    for (int b = tid; b < NB2; b += 256) {
        int cb = hist[b];
        sc[b] = sc[b] - cb;
        gbase[b] = cb ? atomicAdd(&gfill[b], cb) : 0;
        rankc[b] = 0;
    }
    __syncthreads();

    for (int e = e0 + tid; e < e1; e += 256) {
        int r = rows[e];
        int c = cols[e];
        float v = vals[e];
        int b = r >> BSH2;
        int lr = atomicAdd(&rankc[b], 1);
        int lpos = sc[b] + lr;
        st[lpos]   = make_int2(((r & 1023) << 19) | c, __float_as_int(v));
        dstb[lpos] = gbase[b] + lr;
    }
    __syncthreads();

    for (int i = tid; i < n; i += 256)
        estage[dstb[i]] = st[i];
}

// ---------------- pass 2: one block per bucket; builds rowptr, ticket-scatters ----------------
__global__ __launch_bounds__(1024) void row_scatter(const int* __restrict__ bstart,
                                                    const int2* __restrict__ estage,
                                                    int2* __restrict__ epack,
                                                    int* __restrict__ rowptr) {
    __shared__ int lcnt[1024];
    __shared__ int s[1024];
    int b = blockIdx.x;
    int r0 = b << BSH2;
    int nr = min(1024, NN - r0);
    int tid = threadIdx.x;
    lcnt[tid] = 0;
    __syncthreads();

    int ebeg = bstart[b];
    int eend = bstart[b + 1];
    for (int e = ebeg + tid; e < eend; e += 1024)
        atomicAdd(&lcnt[((unsigned)estage[e].x) >> 19], 1);
    __syncthreads();

    int x = lcnt[tid];
    s[tid] = x;
    __syncthreads();
    for (int off = 1; off < 1024; off <<= 1) {
        int t = (tid >= off) ? s[tid - off] : 0;
        __syncthreads();
        s[tid] += t;
        __syncthreads();
    }
    int myptr = ebeg + s[tid] - x;
    if (tid < nr) rowptr[r0 + tid] = myptr;
    lcnt[tid] = myptr;
    __syncthreads();

    for (int e = ebeg + tid; e < eend; e += 1024) {
        int2 ed = estage[e];
        int rl = ((unsigned)ed.x) >> 19;
        int pos = atomicAdd(&lcnt[rl], 1);
        epack[pos] = make_int2(ed.x & 0x7FFFF, ed.y);
    }
    if (b == 0 && tid == 0) rowptr[NN] = N_EDGES;
}

// ---------------- shared row-dot: 8-wide unroll, nt edge-stream loads ----------------
__device__ __forceinline__ float row_dot(const int2* __restrict__ ep, int beg, int end,
                                         const float* __restrict__ Ein, int lane) {
    const long long* epl = (const long long*)ep;   // (col | val<<32) packed, 8 B
    float acc = 0.f;
    int j = beg;
    int jend8 = beg + ((end - beg) & ~7);
    for (; j < jend8; j += 8) {
        long long d[8];
        #pragma unroll
        for (int k = 0; k < 8; ++k) d[k] = __builtin_nontemporal_load(&epl[j + k]);
        float x[8];
        #pragma unroll
        for (int k = 0; k < 8; ++k)
            x[k] = Ein[(size_t)(int)(d[k] & 0x7FFFF) * DIM + lane];
        #pragma unroll
        for (int k = 0; k < 8; ++k)
            acc = __builtin_fmaf(__int_as_float((int)(d[k] >> 32)), x[k], acc);
    }
    if (j + 4 <= end) {
        long long d[4];
        #pragma unroll
        for (int k = 0; k < 4; ++k) d[k] = __builtin_nontemporal_load(&epl[j + k]);
        float x[4];
        #pragma unroll
        for (int k = 0; k < 4; ++k)
            x[k] = Ein[(size_t)(int)(d[k] & 0x7FFFF) * DIM + lane];
        #pragma unroll
        for (int k = 0; k < 4; ++k)
            acc = __builtin_fmaf(__int_as_float((int)(d[k] >> 32)), x[k], acc);
        j += 4;
    }
    for (; j < end; ++j) {
        long long d = __builtin_nontemporal_load(&epl[j]);
        acc = __builtin_fmaf(__int_as_float((int)(d >> 32)),
                             Ein[(size_t)(int)(d & 0x7FFFF) * DIM + lane], acc);
    }
    return acc;
}

// ---------------- SpMM: one wave per row, lane = dim ----------------
__global__ void spmm_csr(const int* __restrict__ rowptr, const int2* __restrict__ ep,
                         const float* __restrict__ Ein, float* __restrict__ Eout) {
    int lane = threadIdx.x & 63;
    int w = (int)((blockIdx.x * (size_t)blockDim.x + threadIdx.x) >> 6);
    int row = __builtin_amdgcn_readfirstlane(w);
    if (row >= NN) return;
    int beg = rowptr[row];
    int end = rowptr[row + 1];
    float acc = row_dot(ep, beg, end, Ein, lane);
    __builtin_nontemporal_store(acc, &Eout[(size_t)row * DIM + lane]);
}

// ---------------- layer 3: SpMM only at the 2*BATCH target rows, fused acc ----------------
__global__ void spmm_target(const int* __restrict__ rowptr, const int2* __restrict__ ep,
                            const float* __restrict__ Ein, const int* __restrict__ U,
                            const int* __restrict__ I, float* __restrict__ accU,
                            float* __restrict__ accI) {
    int lane = threadIdx.x & 63;
    int w = (int)((blockIdx.x * (size_t)blockDim.x + threadIdx.x) >> 6);
    if (w >= 2 * BATCH) return;
    int row;
    float* accp;
    if (w < BATCH) { row = U[w];                   accp = accU + (size_t)w * DIM; }
    else           { row = N_USERS + I[w - BATCH]; accp = accI + (size_t)(w - BATCH) * DIM; }
    row = __builtin_amdgcn_readfirstlane(row);
    int beg = rowptr[row];
    int end = rowptr[row + 1];
    float acc = row_dot(ep, beg, end, Ein, lane);
    accp[lane] += acc;
}

// ---------------- acc at the 2*BATCH target rows ----------------
__global__ void acc_init(const float* __restrict__ E, const int* __restrict__ U,
                         const int* __restrict__ I, float* __restrict__ accU,
                         float* __restrict__ accI) {
    int t = blockIdx.x * blockDim.x + threadIdx.x;
    int b = t >> 6, d = t & 63;
    accU[t] = E[(size_t)U[b] * DIM + d];
    accI[t] = E[(size_t)(N_USERS + I[b]) * DIM + d];
}

__global__ void acc_add(const float* __restrict__ E, const int* __restrict__ U,
                        const int* __restrict__ I, float* __restrict__ accU,
                        float* __restrict__ accI) {
    int t = blockIdx.x * blockDim.x + threadIdx.x;
    int b = t >> 6, d = t & 63;
    accU[t] += E[(size_t)U[b] * DIM + d];
    accI[t] += E[(size_t)(N_USERS + I[b]) * DIM + d];
}

// ---------------- final: out[b] = dot(accU[b], accI[b]) / 16 ----------------
__global__ void dot_out(const float* __restrict__ accU, const float* __restrict__ accI,
                        float* __restrict__ out) {
    int t = blockIdx.x * blockDim.x + threadIdx.x;
    int b = t >> 6, lane = threadIdx.x & 63;
    float p = accU[t] * accI[t];
    #pragma unroll
    for (int off = 32; off; off >>= 1) p += __shfl_xor(p, off, 64);
    if (lane == 0) out[b] = p * (1.0f / 16.0f);
}

extern "C" void kernel_launch(void* const* d_in, const int* in_sizes, int n_in,
                              void* d_out, int out_size, void* d_ws, size_t ws_size,
                              hipStream_t stream) {
    const float* ue   = (const float*)d_in[0];
    const float* ie   = (const float*)d_in[1];
    const float* vals = (const float*)d_in[2];
    const int*   rows = (const int*)d_in[3];
    const int*   cols = (const int*)d_in[4];
    const int*   U    = (const int*)d_in[5];
    const int*   I    = (const int*)d_in[6];
    float* out = (float*)d_out;

    char* ws = (char*)d_ws;
    const size_t Ebytes  = (size_t)NN * DIM * sizeof(float);       // 76.8 MB
    const size_t EPbytes = (size_t)N_EDGES * sizeof(int2);         // 76.8 MB
    const size_t ACbytes = (size_t)BATCH * DIM * sizeof(float);    // 4.2 MB
    const size_t RPbytes = ((size_t)(NN + 1) * sizeof(int) + 255) & ~(size_t)255;
    const size_t NBbytes = (((size_t)(NB2 + 1) * sizeof(int)) + 255) & ~(size_t)255;

    size_t off = 0;
    float* Ecur   = (float*)(ws + off); off += Ebytes;             // aliased by estage pre-copy_init
    float* Enext  = (float*)(ws + off); off += Ebytes;
    int2*  epack  = (int2*)(ws + off);  off += EPbytes;
    float* accU   = (float*)(ws + off); off += ACbytes;
    float* accI   = (float*)(ws + off); off += ACbytes;
    int*   rowptr = (int*)(ws + off);   off += RPbytes;
    int*   bcnt   = (int*)(ws + off);   off += NBbytes;
    int*   bstart = (int*)(ws + off);   off += NBbytes;
    int*   gfill  = (int*)(ws + off);   off += NBbytes;

    // edge staging (8 B/edge) aliases Ecur/Enext region (dead before copy_init runs)
    int2* estage = (int2*)ws;

    const int nBinBlocks = (N_EDGES + CHUNK2 - 1) / CHUNK2;        // 2344

    // --- build CSR ---
    hipMemsetAsync(bcnt, 0, (size_t)(NB2 + 1) * sizeof(int), stream);
    hist_buckets<<<1024, 256, 0, stream>>>(rows, bcnt);
    scan_buckets<<<1, 512, 0, stream>>>(bcnt, bstart, gfill);
    bin_sort<<<nBinBlocks, 256, 0, stream>>>(rows, cols, vals, gfill, estage);
    row_scatter<<<NB2, 1024, 0, stream>>>(bstart, estage, epack, rowptr);

    // --- embeddings + propagation ---
    copy_init<<<2048, 256, 0, stream>>>(ue, ie, Ecur);
    acc_init<<<BATCH * DIM / 256, 256, 0, stream>>>(Ecur, U, I, accU, accI);

    const int spmmBlocks = (NN * 64 + 255) / 256;                  // 1 wave per row
    for (int l = 0; l < 2; ++l) {
        spmm_csr<<<spmmBlocks, 256, 0, stream>>>(rowptr, epack, Ecur, Enext);
        acc_add<<<BATCH * DIM / 256, 256, 0, stream>>>(Enext, U, I, accU, accI);
        float* t = Ecur; Ecur = Enext; Enext = t;
    }
    spmm_target<<<2 * BATCH * 64 / 256, 256, 0, stream>>>(rowptr, epack, Ecur, U, I, accU, accI);

    dot_out<<<BATCH / 4, 256, 0, stream>>>(accU, accI, out);
}